// Round 2
// baseline (3695.242 us; speedup 1.0000x reference)
//
#include <hip/hip_runtime.h>
#include <hip/hip_bf16.h>
#include <hip/hip_cooperative_groups.h>
#include <stdint.h>

namespace cg = cooperative_groups;

typedef __attribute__((ext_vector_type(8))) short bf16x8;
typedef __attribute__((ext_vector_type(4))) float f32x4;
typedef unsigned short u16;
typedef unsigned int u32;

// Problem constants: T=512, B=256, D=H=512, 3H=1536.
// rid = t*256 + b.  ins row = rid*512 f32.  h_prev row = (rid-256)*512 f32 (in ys).

// ---- workspace layout (bytes) ----
static const size_t WS_COUNTS = 0;        // int[512]  cells per depth
static const size_t WS_CURSOR = 2048;     // int[512]  placement cursors
static const size_t WS_MAXD   = 4096;     // int       max depth
static const size_t WS_OFFS   = 4352;     // int[512]  exclusive offsets
static const size_t WS_DARR   = 6400;     // u16[131072] depth per cell, [b][t]
static const size_t WS_LIST   = 268544;   // int[131072] cell ids bucketed by depth
static const size_t WS_WHT    = 794624;   // u16[1536*512]  Wh^T bf16 [n][k]
static const size_t WS_WIT    = WS_WHT + 1572864;  // Wi^T bf16
static const size_t WS_END    = WS_WIT + 1572864;  // ~3.94 MB

union SMem {
  struct {
    u16 A_h[128][72];   // h_prev tile (bf16), one 64-wide K-chunk; pitch 72
    u16 A_x[128][72];   // x tile (bf16)
    u16 W_h[192][72];   // Wh^T tile: rows = gate*64 + hidden_local
    u16 W_i[192][72];
    int rowIds[128];
  } g;
  struct { int a[512]; int b[512]; int c[512]; } p;  // phase A scratch
};

__device__ inline u16 f2bf(float f) {
  u32 x = __float_as_uint(f);
  return (u16)((x + 0x7fffu + ((x >> 16) & 1u)) >> 16);  // RNE
}
__device__ inline u32 pack2(float a, float b) {
  return (u32)f2bf(a) | ((u32)f2bf(b) << 16);
}
__device__ inline float fsig(float x) { return 1.f / (1.f + __expf(-x)); }
__device__ inline float ftanh(float x) { float e = __expf(2.f * x); return 1.f - 2.f / (e + 1.f); }

__global__ __launch_bounds__(512, 2)
void gru_coop(const float* __restrict__ ins, const int* __restrict__ resets,
              const float* __restrict__ Wi, const float* __restrict__ bip,
              const float* __restrict__ Wh, const float* __restrict__ bhn,
              float* __restrict__ ys, char* __restrict__ ws)
{
  __shared__ SMem sm;
  cg::grid_group grid = cg::this_grid();

  int* counts = (int*)(ws + WS_COUNTS);
  int* cursor = (int*)(ws + WS_CURSOR);
  int* gmaxd  = (int*)(ws + WS_MAXD);
  int* offs   = (int*)(ws + WS_OFFS);
  u16* dArr   = (u16*)(ws + WS_DARR);
  int* list   = (int*)(ws + WS_LIST);
  u16* WhT    = (u16*)(ws + WS_WHT);
  u16* WiT    = (u16*)(ws + WS_WIT);

  const int tid   = threadIdx.x;
  const int bid   = blockIdx.x;
  const int nb    = gridDim.x;
  const int lane  = tid & 63;
  const int wid   = tid >> 6;    // 0..7
  const int wr    = wid & 1;     // row half of the 128-row tile
  const int wc    = wid >> 1;    // hidden quarter (16 cols per gate)
  const int q     = lane >> 4;   // 0..3
  const int laneM = lane & 15;

  const int gtid = bid * 512 + tid;
  const int gsz  = nb * 512;

  // ---------- P0: zero meta; transpose+convert weights to bf16 [n][k] ----------
  for (int i = gtid; i < 512; i += gsz) counts[i] = 0;
  if (gtid == 0) *gmaxd = 0;
  for (int i = gtid; i < 1536 * 512; i += gsz) {
    int n = i >> 9, k = i & 511;
    WhT[i] = f2bf(Wh[k * 1536 + n]);
    WiT[i] = f2bf(Wi[k * 1536 + n]);
  }
  grid.sync();

  // ---------- P1: per-b depth via max-scan of reset positions; histogram ----------
  if (bid < 256) {
    const int b = bid;
    const int t = tid;                       // 512 threads == 512 timesteps
    bool rs = (t == 0) || (resets[t * 256 + b] != 0);
    sm.p.a[t] = rs ? t : -1;
    __syncthreads();
    for (int off = 1; off < 512; off <<= 1) {
      int u = (t >= off) ? sm.p.a[t - off] : -1;
      int v = sm.p.a[t];
      __syncthreads();
      sm.p.a[t] = (u > v) ? u : v;
      __syncthreads();
    }
    const int d = t - sm.p.a[t];             // depth within segment
    dArr[b * 512 + t] = (u16)d;
    sm.p.b[t] = 0;
    __syncthreads();
    atomicAdd(&sm.p.b[d], 1);
    __syncthreads();
    if (sm.p.b[t] > 0) { atomicAdd(&counts[t], sm.p.b[t]); atomicMax(gmaxd, t); }
  }
  grid.sync();

  // ---------- P2: exclusive scan counts -> offs, init cursor ----------
  if (bid == 0) {
    sm.p.a[tid] = counts[tid];
    __syncthreads();
    for (int off = 1; off < 512; off <<= 1) {
      int u = (tid >= off) ? sm.p.a[tid - off] : 0;
      int v = sm.p.a[tid];
      __syncthreads();
      sm.p.a[tid] = u + v;
      __syncthreads();
    }
    int e = sm.p.a[tid] - counts[tid];
    offs[tid] = e;
    cursor[tid] = e;
  }
  grid.sync();

  // ---------- P3: place cells into per-depth lists (two-level counting sort) ----------
  if (bid < 256) {
    const int b = bid;
    const int d = (int)dArr[b * 512 + tid];
    sm.p.b[tid] = 0; sm.p.c[tid] = 0;
    __syncthreads();
    atomicAdd(&sm.p.b[d], 1);
    __syncthreads();
    if (sm.p.b[tid] > 0) sm.p.a[tid] = atomicAdd(&cursor[tid], sm.p.b[tid]);
    __syncthreads();
    int r = atomicAdd(&sm.p.c[d], 1);
    list[sm.p.a[d] + r] = (tid << 8) | b;    // rid = t*256 + b
  }
  grid.sync();

  // ---------- P4: super-steps over depth ----------
  const int maxd = *gmaxd;
  for (int s = 0; s <= maxd; ++s) {
    const int n   = counts[s];
    const int off = offs[s];
    if (n > 0) {
      const int rowTiles = (n + 127) >> 7;
      const int tiles = rowTiles * 8;               // 8 col-tiles of 64 hidden each
      for (int tile = bid; tile < tiles; tile += nb) {
        const int rt = tile >> 3, ct = tile & 7;

        __syncthreads();                            // protect prior tile's LDS
        if (tid < 128) {
          int r = rt * 128 + tid;
          sm.g.rowIds[tid] = (r < n) ? list[off + r] : -1;
        }
        __syncthreads();

        f32x4 acc_i[4][3] = {};
        f32x4 acc_h[4][3] = {};

        for (int kc = 0; kc < 8; ++kc) {
          const int k0 = kc * 64;

          // stage A tiles: f32 global -> bf16 LDS (float4 loads, 8B LDS stores)
          #pragma unroll
          for (int ii = 0; ii < 4; ++ii) {
            int idx = tid + ii * 512;               // 0..2047
            int row = idx >> 4, seg = idx & 15;     // 128 rows x 16 segs of 4 f32
            int rid = sm.g.rowIds[row];
            float4 vx = {0.f, 0.f, 0.f, 0.f};
            if (rid >= 0) vx = *(const float4*)(ins + (size_t)rid * 512 + k0 + seg * 4);
            uint2 px; px.x = pack2(vx.x, vx.y); px.y = pack2(vx.z, vx.w);
            *(uint2*)&sm.g.A_x[row][seg * 4] = px;
            if (s > 0) {
              float4 vh = {0.f, 0.f, 0.f, 0.f};
              if (rid >= 0) vh = *(const float4*)(ys + (size_t)(rid - 256) * 512 + k0 + seg * 4);
              uint2 ph; ph.x = pack2(vh.x, vh.y); ph.y = pack2(vh.z, vh.w);
              *(uint2*)&sm.g.A_h[row][seg * 4] = ph;
            }
          }
          // stage W tiles from pre-transposed bf16 [n][k] copies (16B loads)
          #pragma unroll
          for (int ii = 0; ii < 3; ++ii) {
            int idx = tid + ii * 512;               // 0..1535
            int row = idx >> 3, seg = idx & 7;      // row 0..191
            int g = row >> 6, jl = row & 63;
            size_t src = (size_t)((g << 9) + (ct << 6) + jl) * 512 + k0 + seg * 8;
            *(uint4*)&sm.g.W_i[row][seg * 8] = *(const uint4*)(WiT + src);
            if (s > 0)
              *(uint4*)&sm.g.W_h[row][seg * 8] = *(const uint4*)(WhT + src);
          }
          __syncthreads();

          #pragma unroll
          for (int ks = 0; ks < 2; ++ks) {
            const int kk = ks * 32 + q * 8;
            bf16x8 ax[4], ah[4], wbi[3], wbh[3];
            #pragma unroll
            for (int rf = 0; rf < 4; ++rf) {
              int m = wr * 64 + rf * 16 + laneM;
              ax[rf] = *(const bf16x8*)&sm.g.A_x[m][kk];
              if (s > 0) ah[rf] = *(const bf16x8*)&sm.g.A_h[m][kk];
            }
            #pragma unroll
            for (int cf = 0; cf < 3; ++cf) {
              int wrow = cf * 64 + wc * 16 + laneM;
              wbi[cf] = *(const bf16x8*)&sm.g.W_i[wrow][kk];
              if (s > 0) wbh[cf] = *(const bf16x8*)&sm.g.W_h[wrow][kk];
            }
            #pragma unroll
            for (int rf = 0; rf < 4; ++rf)
              #pragma unroll
              for (int cf = 0; cf < 3; ++cf) {
                acc_i[rf][cf] = __builtin_amdgcn_mfma_f32_16x16x32_bf16(ax[rf], wbi[cf], acc_i[rf][cf], 0, 0, 0);
                if (s > 0)
                  acc_h[rf][cf] = __builtin_amdgcn_mfma_f32_16x16x32_bf16(ah[rf], wbh[cf], acc_h[rf][cf], 0, 0, 0);
              }
          }
          __syncthreads();
        }

        // ---- fused GRU epilogue; h_new written straight to ys (f32) ----
        {
          const int jl = wc * 16 + laneM;     // [0,64)
          const int jg = ct * 64 + jl;        // hidden index [0,512)
          const float bir = bip[jg];
          const float biz = bip[512 + jg];
          const float bin = bip[1024 + jg];
          const float bhv = bhn[jg];
          #pragma unroll
          for (int rf = 0; rf < 4; ++rf) {
            #pragma unroll
            for (int reg = 0; reg < 4; ++reg) {
              const int m = wr * 64 + rf * 16 + q * 4 + reg;
              const int rid = sm.g.rowIds[m];
              if (rid < 0) continue;
              float air = acc_i[rf][0][reg] + bir;
              float aiz = acc_i[rf][1][reg] + biz;
              float ain = acc_i[rf][2][reg] + bin;
              float ahr = 0.f, ahz = 0.f, ahn = 0.f, hp = 0.f;
              if (s > 0) {
                ahr = acc_h[rf][0][reg];
                ahz = acc_h[rf][1][reg];
                ahn = acc_h[rf][2][reg];
                hp  = ys[(size_t)(rid - 256) * 512 + jg];   // f32 carry, exact passthrough
              }
              float r  = fsig(air + ahr);
              float z  = fsig(aiz + ahz);
              float nn = ftanh(ain + r * (ahn + bhv));
              float hnew = (1.f - z) * nn + z * hp;
              ys[(size_t)rid * 512 + jg] = hnew;
            }
          }
        }
      }
    }
    grid.sync();
  }
}

extern "C" void kernel_launch(void* const* d_in, const int* in_sizes, int n_in,
                              void* d_out, int out_size, void* d_ws, size_t ws_size,
                              hipStream_t stream)
{
  if (ws_size < WS_END) return;  // needs ~4 MB scratch
  const float* ins    = (const float*)d_in[0];
  const int*   resets = (const int*)d_in[1];
  // d_in[2] = h0 (all zeros by construction; depth-0 cells start from h=0)
  const float* Wi  = (const float*)d_in[3];
  const float* bi  = (const float*)d_in[4];
  const float* Wh  = (const float*)d_in[5];
  const float* bhn = (const float*)d_in[6];
  float* ys = (float*)d_out;
  char*  ws = (char*)d_ws;

  void* args[8] = { (void*)&ins, (void*)&resets, (void*)&Wi, (void*)&bi,
                    (void*)&Wh, (void*)&bhn, (void*)&ys, (void*)&ws };
  hipLaunchCooperativeKernel((const void*)gru_coop, dim3(256), dim3(512), args, 0, stream);
}